// Round 15
// baseline (42.258 us; speedup 1.0000x reference)
//
#include <hip/hip_runtime.h>

#define NBATCH 16
#define NANCH  3
#define NGRID  64
#define NT     60
#define NPB    (NANCH*NGRID*NGRID)   // 12288 cells per batch
#define NCELL  (NBATCH*NPB)          // 196608 total cells
#define NLBL   (NBATCH*NT)           // 960 labels
#define NBPB   (NPB/256)             // 48 cell-blocks per batch
#define NBLKB  (NBATCH*NBPB)         // 768 kB blocks
#define FEPS   1e-16f

__device__ __forceinline__ float frcp(float x) { return __builtin_amdgcn_rcpf(x); }
__device__ __forceinline__ float sigm(float x) { return frcp(1.0f + __expf(-x)); }

__device__ __forceinline__ float waveSum(float v) {
#pragma unroll
    for (int o = 32; o > 0; o >>= 1) v += __shfl_down(v, o, 64);
    return v;
}
__device__ __forceinline__ double waveSumD(double v) {
#pragma unroll
    for (int o = 32; o > 0; o >>= 1) v += __shfl_down(v, o, 64);
    return v;
}

__device__ __forceinline__ unsigned int ford(float f) {
    unsigned int u = __float_as_uint(f);
    return (u & 0x80000000u) ? ~u : (u | 0x80000000u);
}
__device__ __forceinline__ float ford_inv(unsigned int u) {
    unsigned int v = (u & 0x80000000u) ? (u & 0x7fffffffu) : ~u;
    return __uint_as_float(v);
}

// fused gou: iou - (ca-un)/(ca+eps) == (inter*ce - (ca-un)*ue) / (ue*ce)
__device__ __forceinline__ float gou_f(float px1, float py1, float px2, float py2, float pa,
                                       float gx1, float gy1, float gx2, float gy2, float ga) {
    float iw = fmaxf(fminf(px2, gx2) - fmaxf(px1, gx1), 0.f);
    float ih = fmaxf(fminf(py2, gy2) - fmaxf(py1, gy1), 0.f);
    float inter = iw * ih;
    float un = pa + ga - inter;
    float cw = fmaxf(px2, gx2) - fminf(px1, gx1);
    float ch = fmaxf(py2, gy2) - fminf(py1, gy1);
    float ca = cw * ch;
    float ue = un + FEPS, ce = ca + FEPS;
    return (inter * ce - (ca - un) * ue) * frcp(ue * ce);
}
__device__ __forceinline__ float iou_f(float px1, float py1, float px2, float py2, float pa,
                                       float gx1, float gy1, float gx2, float gy2, float ga) {
    float iw = fmaxf(fminf(px2, gx2) - fmaxf(px1, gx1), 0.f);
    float ih = fmaxf(fminf(py2, gy2) - fmaxf(py1, gy1), 0.f);
    float inter = iw * ih;
    float un = pa + ga - inter;
    return inter * frcp(un + FEPS);
}

// ---------------------------------------------------------------------------
// Kernel B: 768 blocks, 256 cells each. Eval-sharing via LDS gou matrix in
// FOUR quarter-tiles of 64 cells (GM[64][61] = 15.6 KB) — total LDS ~27 KB
// -> 5 blocks/CU (was 3 at half-tiles) -> 20 waves/CU for latency hiding;
// the entire 768-block grid is co-resident. Same eval set, same in-lane
// ascending-n chains, same packed-key block max => bit-exact vs r14.
// ---------------------------------------------------------------------------
__global__ __launch_bounds__(256)
void kB(const float* __restrict__ out, const float* __restrict__ labels,
        const float4* __restrict__ io4, const float4* __restrict__ hm4,
        unsigned long long* __restrict__ gtpart, float4* __restrict__ gtaux,
        double* __restrict__ bpart, unsigned int* __restrict__ ticket) {
    int blk = blockIdx.x, thr = threadIdx.x;
    if (blk == 0 && thr == 0) *ticket = 0u;    // stream order: visible to kD

    int b = blk / NBPB;
    int s = blk - b * NBPB;
    int n = s * 256 + thr;                     // cell within batch
    int idx = b * NPB + n;
    int wave = thr >> 6, lane = thr & 63;

    __shared__ float4 G4[NT];
    __shared__ float  GA[NT];
    __shared__ float4 Bxy[256];
    __shared__ float  Bpa[256];
    __shared__ float  GM[64][61];              // quarter-tile gou matrix (15.6 KB)
    __shared__ float  pdG[256], pdI[256], cfL[256];
    __shared__ unsigned long long W[4][NT];
    __shared__ unsigned int obits[8];          // block-local obj bits (256 cells)
    __shared__ int keys[NT];
    __shared__ float red[8][4];

    if (thr < 8) obits[thr] = 0u;
    if (thr < NT) {
        const float* lp = labels + (b * NT + thr) * 5;
        float gx = lp[1], gy = lp[2], gw = lp[3], gh = lp[4];
        G4[thr] = make_float4(gx - gw * 0.5f, gy - gh * 0.5f,
                              gx + gw * 0.5f, gy + gh * 0.5f);
        GA[thr] = gw * gh;
        keys[thr] = ((int)(gy * (float)NGRID) << 6) | (int)(gx * (float)NGRID);
    }

    int a = n >> 12, gj = (n >> 6) & 63, gi = n & 63;
    int base = ((b * NANCH * 5 + a * 5) * NGRID + gj) * NGRID + gi;
    float xs = sigm(out[base]);
    float ys = sigm(out[base + NGRID * NGRID]);
    float ws = sigm(out[base + 2 * NGRID * NGRID]);
    float hs = sigm(out[base + 3 * NGRID * NGRID]);
    float cf = sigm(out[base + 4 * NGRID * NGRID]);

    float bx = (xs + (float)gi) * (1.0f / NGRID);
    float by = (ys + (float)gj) * (1.0f / NGRID);
    float px1 = bx - ws * 0.5f, px2 = bx + ws * 0.5f;
    float py1 = by - hs * 0.5f, py2 = by + hs * 0.5f;
    float pa = ws * hs;

    Bxy[thr] = make_float4(px1, py1, px2, py2);
    Bpa[thr] = pa;
    cfL[thr] = cf;
    __syncthreads();                           // G4/GA/keys + boxes ready

    // block-local obj bits: occ scan over this batch's 60 labels
    if (thr < NT) {
        int key = keys[thr];
        int occ = 0;
        for (int i = 0; i < thr; ++i)
            if (keys[i] == key) occ++;
        if (occ < NANCH) {
            int cell = (occ << 12) | key;               // batch-local n
            int lc = cell - s * 256;
            if (lc >= 0 && lc < 256) atomicOr(&obits[lc >> 5], 1u << (lc & 31));
        }
    }

    // --- four quarter-tiles: gt-side eval (writes GM) then pd-side (reads GM)
    int t = (lane < NT) ? lane : 0;
    float4 gt4 = G4[t];
    float gta = GA[t];
    unsigned long long bp = 0ull;              // per-lane running gt winner
    float bg = -1e30f, biou = 0.0f;            // this thread's pd result

#pragma unroll
    for (int h = 0; h < 4; ++h) {
        // gt-side: wave scans 16 cells of quarter h via LDS broadcast; lane = t
        int cb = h * 64 + wave * 16;
        int nb = s * 256 + cb;
#pragma unroll 4
        for (int i = 0; i < 16; ++i) {
            int c = cb + i;
            float4 p = Bxy[c];                 // wave-uniform address: broadcast
            float cpa = Bpa[c];
            float gou = gou_f(p.x, p.y, p.z, p.w, cpa,
                              gt4.x, gt4.y, gt4.z, gt4.w, gta);
            if (lane < NT) GM[c - h * 64][lane] = gou;
            unsigned long long pk = ((unsigned long long)ford(gou) << 32)
                                  | (0xFFFFFFFFu - (unsigned int)(nb + i));
            if (pk > bp) bp = pk;              // ascending n + strict > = first-index
        }
        __syncthreads();                       // GM quarter complete

        // pd-side: wave h argmaxes its own 64 cells via LDS reads (stride 61
        // -> odd stride -> 2 lanes/bank, conflict-free)
        if (wave == h) {
            float bg0 = -1e30f, bg1 = -1e30f;
            int bt0 = 0, bt1 = NT / 2;
#pragma unroll 2
            for (int tt = 0; tt < NT / 2; ++tt) {
                float g0 = GM[lane][tt];
                if (g0 > bg0) { bg0 = g0; bt0 = tt; }
                float g1 = GM[lane][tt + NT / 2];
                if (g1 > bg1) { bg1 = g1; bt1 = tt + NT / 2; }
            }
            bg = bg0;
            int bt = bt0;
            if (bg1 > bg0) { bg = bg1; bt = bt1; }
            float4 gb = G4[bt];
            biou = iou_f(px1, py1, px2, py2, pa, gb.x, gb.y, gb.z, gb.w, GA[bt]);
            pdG[thr] = bg;
            pdI[thr] = biou;
        }
        __syncthreads();                       // before GM reuse
    }
    if (lane < NT) W[wave][lane] = bp;
    __syncthreads();                           // W + pdG/pdI + obits complete

    // block winner per t -> gtpart + aux (iou_w, cf, pdg, pdi of winner cell)
    if (thr < NT) {
        unsigned long long pk = W[0][thr];
        if (W[1][thr] > pk) pk = W[1][thr];
        if (W[2][thr] > pk) pk = W[2][thr];
        if (W[3][thr] > pk) pk = W[3][thr];
        int wn = (int)(0xFFFFFFFFu - (unsigned int)(pk & 0xFFFFFFFFu));
        int lc = wn - s * 256;
        float4 p = Bxy[lc];
        float4 g = G4[thr];
        float iw = iou_f(p.x, p.y, p.z, p.w, Bpa[lc], g.x, g.y, g.z, g.w, GA[thr]);
        gtpart[blk * 64 + thr] = pk;
        gtaux [blk * 64 + thr] = make_float4(iw, cfL[lc], pdG[lc], pdI[lc]);
    }

    // --- 8 per-block partials: mask_-free base sums + pg + hm
    bool mk = (biou >= 0.5f);
    bool ob = (obits[thr >> 5] >> (thr & 31)) & 1u;
    float fmk = mk ? 1.f : 0.f, fnmk = 1.f - fmk, fob = ob ? 1.f : 0.f;
    float4 ha = io4[idx], hb = hm4[idx];
    float d0 = ha.x - hb.x, d1 = ha.y - hb.y, d2 = ha.z - hb.z, d3 = ha.w - hb.w;
    float vals[8] = {
        fmk,                          // c2 base  (sum mk)
        (1.f - bg) * fmk,             // sg base
        (1.f - biou) * fmk,           // si base
        cf * fob * fnmk,              // sint base (cf*ob*!mk)
        cf * cf * fnmk,               // spa base  (cf^2*!mk)
        fob * fnmk,                   // sga base  (ob*!mk)
        cf * cf,                      // pg
        d0 * d0 + d1 * d1 + d2 * d2 + d3 * d3   // hm
    };
#pragma unroll
    for (int k = 0; k < 8; ++k) {
        float vv = waveSum(vals[k]);
        if (lane == 0) red[k][wave] = vv;
    }
    __syncthreads();
    if (thr == 0) {
#pragma unroll
        for (int k = 0; k < 8; ++k)
            bpart[blk * 8 + k] = (double)(red[k][0] + red[k][1] + red[k][2] + red[k][3]);
    }
}

// ---------------------------------------------------------------------------
// Kernel D (slim, r10/r13-proven, unchanged): 16 blocks. Label pass; 60x48
// winner scan; dedup'd winner-cell corrections; 48-row partial sum; bacc row
// + fence + ticket; last block finalizes. Producer->consumer coherence via
// the kernel boundary (the only mechanism proven on this chip).
// ---------------------------------------------------------------------------
__global__ __launch_bounds__(256)
void kD(const float* __restrict__ out, const float* __restrict__ labels,
        const unsigned long long* __restrict__ gtpart, const float4* __restrict__ gtaux,
        const double* __restrict__ bpart,
        double* __restrict__ bacc, unsigned int* __restrict__ ticket,
        float* __restrict__ outp) {
    int b = blockIdx.x, thr = threadIdx.x;
    int wave = thr >> 6, lane = thr & 63;

    __shared__ int keys[NT];
    __shared__ unsigned int obits[NPB / 32];   // 384 words (full batch)
    __shared__ int wnL[NT];
    __shared__ float4 auxL[NT];
    __shared__ int finS;
    __shared__ double baccL[256];

    for (int w = thr; w < NPB / 32; w += 256) obits[w] = 0u;
    if (thr < NT) {
        const float* lp = labels + (b * NT + thr) * 5;
        keys[thr] = ((int)(lp[2] * (float)NGRID) << 6) | (int)(lp[1] * (float)NGRID);
    }
    __syncthreads();

    float sxy = 0.f, swh = 0.f, sig_ = 0.f, scnt = 0.f, sgou = 0.f, siou = 0.f;
    if (thr < NT) {
        // label pass
        int key = keys[thr];
        int occ = 0;
        for (int i = 0; i < thr; ++i)
            if (keys[i] == key) occ++;
        const float* lp = labels + (b * NT + thr) * 5;
        float bxf = lp[1] * (float)NGRID;
        float byf = lp[2] * (float)NGRID;
        float lw_ = lp[3], lh_ = lp[4];
        int gi = (int)bxf, gj = (int)byf;
        if (occ < NANCH) {
            int cell = (occ << 12) | (gj << 6) | gi;
            atomicOr(&obits[cell >> 5], 1u << (cell & 31));
            int base = ((b * NANCH * 5 + occ * 5) * NGRID + gj) * NGRID + gi;
            float xs = sigm(out[base]);
            float ys = sigm(out[base + NGRID * NGRID]);
            float ws = sigm(out[base + 2 * NGRID * NGRID]);
            float hs = sigm(out[base + 3 * NGRID * NGRID]);
            float cfl = sigm(out[base + 4 * NGRID * NGRID]);
            float tx = bxf - floorf(bxf);
            float ty = byf - floorf(byf);
            float dx = xs - tx, dy = ys - ty;
            sxy = dx * dx + dy * dy;
            float dw = __logf(ws) - __logf(lw_);
            float dh = __logf(hs) - __logf(lh_);
            swh = dw * dw + dh * dh;
            sig_ = cfl;
            scnt = 1.f;
        }
        // winner scan over this batch's 48 block winners for GT thr
        unsigned long long bestp = 0ull;
        int sbest = 0;
        for (int ss = 0; ss < NBPB; ++ss) {
            unsigned long long pk = gtpart[(b * NBPB + ss) * 64 + thr];
            if (pk > bestp) { bestp = pk; sbest = ss; }   // pk unique across ss
        }
        float4 aux = gtaux[(b * NBPB + sbest) * 64 + thr];
        wnL[thr] = (int)(0xFFFFFFFFu - (unsigned int)(bestp & 0xFFFFFFFFu));
        auxL[thr] = aux;
        sgou = 1.f - ford_inv((unsigned int)(bestp >> 32));
        siou = 1.f - aux.x;
    }
    __syncthreads();   // obits + wnL/auxL complete

    // dedup'd winner-cell corrections (first t claims the cell)
    float dc2 = 0.f, dsg = 0.f, dsi = 0.f, dsint = 0.f, dspa = 0.f, dsga = 0.f;
    if (thr < NT) {
        int wn = wnL[thr];
        bool uniq = true;
        for (int tp = 0; tp < thr; ++tp)
            if (wnL[tp] == wn) { uniq = false; break; }
        if (uniq) {
            float4 aux = auxL[thr];            // (iou_w, cf, pdg, pdi)
            bool mk = (aux.w >= 0.5f);
            bool ob = (obits[wn >> 5] >> (wn & 31)) & 1u;
            float fnmk = mk ? 0.f : 1.f;
            float obnmk = (ob ? 1.f : 0.f) * fnmk;
            dc2 = fnmk;
            dsg = (1.f - aux.z) * fnmk;
            dsi = (1.f - aux.w) * fnmk;
            dsint = aux.y * (1.f - obnmk);
            dspa = aux.y * aux.y * (mk ? 1.f : 0.f);
            dsga = 1.f - obnmk;
        }
    }

    // wave-0 reductions + 48-row partial sums
    double labD[6], corD[6], prtD[8];
    if (wave == 0) {
        labD[0] = (double)waveSum(sxy);
        labD[1] = (double)waveSum(swh);
        labD[2] = (double)waveSum(sig_);
        labD[3] = (double)waveSum(scnt);
        labD[4] = (double)waveSum(sgou);
        labD[5] = (double)waveSum(siou);
        corD[0] = (double)waveSum(dc2);
        corD[1] = (double)waveSum(dsg);
        corD[2] = (double)waveSum(dsi);
        corD[3] = (double)waveSum(dsint);
        corD[4] = (double)waveSum(dspa);
        corD[5] = (double)waveSum(dsga);
#pragma unroll
        for (int k = 0; k < 8; ++k) {
            double v = (lane < NBPB) ? bpart[(b * NBPB + lane) * 8 + k] : 0.0;
            prtD[k] = waveSumD(v);
        }
    }
    __syncthreads();

    // bacc row + release fence + ticket
    if (thr == 0) {
        double* row = &bacc[b * 16];
        row[0]  = prtD[0] + corD[0];   // c2
        row[1]  = prtD[1] + corD[1];   // sg
        row[2]  = prtD[2] + corD[2];   // si
        row[3]  = prtD[3] + corD[3];   // sinter
        row[4]  = prtD[4] + corD[4];   // spa
        row[5]  = prtD[5] + corD[5];   // sga
        row[6]  = labD[4];             // sgou
        row[7]  = labD[5];             // siou
        row[8]  = labD[0];             // sxy
        row[9]  = labD[1];             // swh
        row[10] = labD[2];             // ig
        row[11] = labD[3];             // cnt
        row[12] = prtD[6];             // pg
        row[13] = prtD[7];             // hm
        row[14] = 0.0; row[15] = 0.0;
        __threadfence();
        unsigned int old = atomicAdd(ticket, 1u);
        finS = (old == NBATCH - 1) ? 1 : 0;
    }
    __syncthreads();

    // finalize (last-finishing block; block-uniform branch)
    if (finS) {
        int bb = thr >> 4, k = thr & 15;
        baccL[thr] = atomicAdd(&bacc[bb * 16 + k], 0.0);   // coherent RMW read
        __syncthreads();
        if (thr == 0) {
            double cnt = 0, sxyT = 0, swhT = 0, igT = 0, pgT = 0, hmT = 0;
            double sgouT = 0, siouT = 0, gou2 = 0, iou2 = 0, confbT = 0;
            for (int q = 0; q < NBATCH; ++q) {
                const double* r = &baccL[q * 16];
                cnt += r[11]; sxyT += r[8]; swhT += r[9]; igT += r[10];
                pgT += r[12]; hmT += r[13];
                sgouT += r[6]; siouT += r[7];
                gou2 += r[1] / r[0];
                iou2 += r[2] / r[0];
                confbT += 1.0 - (2.0 * r[3] + 1.0) / (r[4] + r[5] + 1.0);
            }
            double lxy = sxyT / cnt;
            double lwh = swhT / cnt;
            double lgou = sgouT / (double)NLBL + gou2 / (double)NBATCH;
            double liou = siouT / (double)NLBL + iou2 / (double)NBATCH;
            double dice = (2.0 * igT + 1.0) / (pgT + cnt + 1.0);
            if (dice != dice) dice = 1.0;
            double lconf = 1.0 - dice + confbT / (double)NBATCH;
            double total = lxy + lwh + lconf + lgou;
            double hmv = hmT / (double)(4 * NCELL);
            outp[0] = (float)lxy;
            outp[1] = (float)lwh;
            outp[2] = (float)lconf;
            outp[3] = (float)liou;
            outp[4] = (float)lgou;
            outp[5] = (float)total;
            outp[6] = (float)hmv;
        }
    }
}

// ---------------------------------------------------------------------------
extern "C" void kernel_launch(void* const* d_in, const int* in_sizes, int n_in,
                              void* d_out, int out_size, void* d_ws, size_t ws_size,
                              hipStream_t stream) {
    const float* out_p  = (const float*)d_in[0];
    const float* labels = (const float*)d_in[1];
    const float4* io4   = (const float4*)d_in[2];
    const float4* hm4   = (const float4*)d_in[3];
    float* o = (float*)d_out;

    char* ws = (char*)d_ws;
    unsigned long long* gtpart = (unsigned long long*)(ws);            // 393216 B
    float4* gtaux = (float4*)(ws + 393216);                            // 786432 B
    double* bpart = (double*)(ws + 1179648);                           //  49152 B
    double* bacc  = (double*)(ws + 1228800);                           //   2048 B
    unsigned int* ticket = (unsigned int*)(ws + 1230848);              //     64 B
    // ~1.23 MB total; all consumed data fully written each call (kB zeroes
    // the ticket) — no memset, no zero-init ordering hazards. Producer ->
    // consumer crosses the kernel boundary (the only coherence mechanism
    // proven on this chip: r11/r12 intra-dispatch attempts both failed).

    hipLaunchKernelGGL(kB, dim3(NBLKB), dim3(256), 0, stream, out_p, labels, io4, hm4,
                       gtpart, gtaux, bpart, ticket);
    hipLaunchKernelGGL(kD, dim3(NBATCH), dim3(256), 0, stream, out_p, labels,
                       gtpart, gtaux, bpart, bacc, ticket, o);
}

// Round 16
// 39.984 us; speedup vs baseline: 1.0569x; 1.0569x over previous
//
#include <hip/hip_runtime.h>

#define NBATCH 16
#define NANCH  3
#define NGRID  64
#define NT     60
#define NPB    (NANCH*NGRID*NGRID)   // 12288 cells per batch
#define NCELL  (NBATCH*NPB)          // 196608 total cells
#define NLBL   (NBATCH*NT)           // 960 labels
#define NBPB   (NPB/256)             // 48 cell-blocks per batch
#define NBLKB  (NBATCH*NBPB)         // 768 kB blocks
#define FEPS   1e-16f

__device__ __forceinline__ float frcp(float x) { return __builtin_amdgcn_rcpf(x); }
__device__ __forceinline__ float sigm(float x) { return frcp(1.0f + __expf(-x)); }

__device__ __forceinline__ float waveSum(float v) {
#pragma unroll
    for (int o = 32; o > 0; o >>= 1) v += __shfl_down(v, o, 64);
    return v;
}
__device__ __forceinline__ double waveSumD(double v) {
#pragma unroll
    for (int o = 32; o > 0; o >>= 1) v += __shfl_down(v, o, 64);
    return v;
}

__device__ __forceinline__ unsigned int ford(float f) {
    unsigned int u = __float_as_uint(f);
    return (u & 0x80000000u) ? ~u : (u | 0x80000000u);
}
__device__ __forceinline__ float ford_inv(unsigned int u) {
    unsigned int v = (u & 0x80000000u) ? (u & 0x7fffffffu) : ~u;
    return __uint_as_float(v);
}

// fused gou: iou - (ca-un)/(ca+eps) == (inter*ce - (ca-un)*ue) / (ue*ce)
__device__ __forceinline__ float gou_f(float px1, float py1, float px2, float py2, float pa,
                                       float gx1, float gy1, float gx2, float gy2, float ga) {
    float iw = fmaxf(fminf(px2, gx2) - fmaxf(px1, gx1), 0.f);
    float ih = fmaxf(fminf(py2, gy2) - fmaxf(py1, gy1), 0.f);
    float inter = iw * ih;
    float un = pa + ga - inter;
    float cw = fmaxf(px2, gx2) - fminf(px1, gx1);
    float ch = fmaxf(py2, gy2) - fminf(py1, gy1);
    float ca = cw * ch;
    float ue = un + FEPS, ce = ca + FEPS;
    return (inter * ce - (ca - un) * ue) * frcp(ue * ce);
}
__device__ __forceinline__ float iou_f(float px1, float py1, float px2, float py2, float pa,
                                       float gx1, float gy1, float gx2, float gy2, float ga) {
    float iw = fmaxf(fminf(px2, gx2) - fmaxf(px1, gx1), 0.f);
    float ih = fmaxf(fminf(py2, gy2) - fmaxf(py1, gy1), 0.f);
    float inter = iw * ih;
    float un = pa + ga - inter;
    return inter * frcp(un + FEPS);
}

// ---------------------------------------------------------------------------
// Kernel B (r14-proven, best measured: 39.94us total): 768 blocks, 256 cells
// each. Eval-sharing via LDS gou matrix in two 128-cell half-tiles
// (GM[128][61] = 31.2 KB, odd stride => conflict-free): the gt-side
// lane-per-GT loop writes gou to GM; the pd-side argmaxes over LDS READS —
// each (cell,GT) pair evaluated exactly ONCE (algorithmic minimum).
// Quarter-tile variant (r15) regressed: more barriers cost more than the
// occupancy gain bought. This configuration is the measured optimum.
// ---------------------------------------------------------------------------
__global__ __launch_bounds__(256)
void kB(const float* __restrict__ out, const float* __restrict__ labels,
        const float4* __restrict__ io4, const float4* __restrict__ hm4,
        unsigned long long* __restrict__ gtpart, float4* __restrict__ gtaux,
        double* __restrict__ bpart, unsigned int* __restrict__ ticket) {
    int blk = blockIdx.x, thr = threadIdx.x;
    if (blk == 0 && thr == 0) *ticket = 0u;    // stream order: visible to kD

    int b = blk / NBPB;
    int s = blk - b * NBPB;
    int n = s * 256 + thr;                     // cell within batch
    int idx = b * NPB + n;
    int wave = thr >> 6, lane = thr & 63;

    __shared__ float4 G4[NT];
    __shared__ float  GA[NT];
    __shared__ float4 Bxy[256];
    __shared__ float  Bpa[256];
    __shared__ float  GM[128][61];             // half-tile gou matrix (31.2 KB)
    __shared__ float  pdG[256], pdI[256], cfL[256];
    __shared__ unsigned long long W[4][NT];
    __shared__ unsigned int obits[8];          // block-local obj bits (256 cells)
    __shared__ int keys[NT];
    __shared__ float red[8][4];

    if (thr < 8) obits[thr] = 0u;
    if (thr < NT) {
        const float* lp = labels + (b * NT + thr) * 5;
        float gx = lp[1], gy = lp[2], gw = lp[3], gh = lp[4];
        G4[thr] = make_float4(gx - gw * 0.5f, gy - gh * 0.5f,
                              gx + gw * 0.5f, gy + gh * 0.5f);
        GA[thr] = gw * gh;
        keys[thr] = ((int)(gy * (float)NGRID) << 6) | (int)(gx * (float)NGRID);
    }

    int a = n >> 12, gj = (n >> 6) & 63, gi = n & 63;
    int base = ((b * NANCH * 5 + a * 5) * NGRID + gj) * NGRID + gi;
    float xs = sigm(out[base]);
    float ys = sigm(out[base + NGRID * NGRID]);
    float ws = sigm(out[base + 2 * NGRID * NGRID]);
    float hs = sigm(out[base + 3 * NGRID * NGRID]);
    float cf = sigm(out[base + 4 * NGRID * NGRID]);

    float bx = (xs + (float)gi) * (1.0f / NGRID);
    float by = (ys + (float)gj) * (1.0f / NGRID);
    float px1 = bx - ws * 0.5f, px2 = bx + ws * 0.5f;
    float py1 = by - hs * 0.5f, py2 = by + hs * 0.5f;
    float pa = ws * hs;

    Bxy[thr] = make_float4(px1, py1, px2, py2);
    Bpa[thr] = pa;
    cfL[thr] = cf;
    __syncthreads();                           // G4/GA/keys + boxes ready

    // block-local obj bits: occ scan over this batch's 60 labels
    if (thr < NT) {
        int key = keys[thr];
        int occ = 0;
        for (int i = 0; i < thr; ++i)
            if (keys[i] == key) occ++;
        if (occ < NANCH) {
            int cell = (occ << 12) | key;               // batch-local n
            int lc = cell - s * 256;
            if (lc >= 0 && lc < 256) atomicOr(&obits[lc >> 5], 1u << (lc & 31));
        }
    }

    // --- two half-tiles: gt-side eval (writes GM) then pd-side (reads GM)
    int t = (lane < NT) ? lane : 0;
    float4 gt4 = G4[t];
    float gta = GA[t];
    unsigned long long bp = 0ull;              // per-lane running gt winner
    float bg = -1e30f, biou = 0.0f;            // this thread's pd result

#pragma unroll
    for (int h = 0; h < 2; ++h) {
        // gt-side: wave scans 32 cells of half h via LDS broadcast; lane = t
        int cb = h * 128 + wave * 32;
        int nb = s * 256 + cb;
#pragma unroll 4
        for (int i = 0; i < 32; ++i) {
            int c = cb + i;
            float4 p = Bxy[c];                 // wave-uniform address: broadcast
            float cpa = Bpa[c];
            float gou = gou_f(p.x, p.y, p.z, p.w, cpa,
                              gt4.x, gt4.y, gt4.z, gt4.w, gta);
            if (lane < NT) GM[c - h * 128][lane] = gou;
            unsigned long long pk = ((unsigned long long)ford(gou) << 32)
                                  | (0xFFFFFFFFu - (unsigned int)(nb + i));
            if (pk > bp) bp = pk;              // ascending n + strict > = first-index
        }
        __syncthreads();                       // GM half complete

        // pd-side for this half's 128 cells: LDS reads, dual-chain argmax
        if ((thr >> 7) == h) {
            int lc = thr & 127;
            float bg0 = -1e30f, bg1 = -1e30f;
            int bt0 = 0, bt1 = NT / 2;
#pragma unroll 2
            for (int tt = 0; tt < NT / 2; ++tt) {
                float g0 = GM[lc][tt];
                if (g0 > bg0) { bg0 = g0; bt0 = tt; }
                float g1 = GM[lc][tt + NT / 2];
                if (g1 > bg1) { bg1 = g1; bt1 = tt + NT / 2; }
            }
            bg = bg0;
            int bt = bt0;
            if (bg1 > bg0) { bg = bg1; bt = bt1; }
            float4 gb = G4[bt];
            biou = iou_f(px1, py1, px2, py2, pa, gb.x, gb.y, gb.z, gb.w, GA[bt]);
            pdG[thr] = bg;
            pdI[thr] = biou;
        }
        __syncthreads();                       // before GM reuse / W write
    }
    if (lane < NT) W[wave][lane] = bp;
    __syncthreads();                           // W + pdG/pdI + obits complete

    // block winner per t -> gtpart + aux (iou_w, cf, pdg, pdi of winner cell)
    if (thr < NT) {
        unsigned long long pk = W[0][thr];
        if (W[1][thr] > pk) pk = W[1][thr];
        if (W[2][thr] > pk) pk = W[2][thr];
        if (W[3][thr] > pk) pk = W[3][thr];
        int wn = (int)(0xFFFFFFFFu - (unsigned int)(pk & 0xFFFFFFFFu));
        int lc = wn - s * 256;
        float4 p = Bxy[lc];
        float4 g = G4[thr];
        float iw = iou_f(p.x, p.y, p.z, p.w, Bpa[lc], g.x, g.y, g.z, g.w, GA[thr]);
        gtpart[blk * 64 + thr] = pk;
        gtaux [blk * 64 + thr] = make_float4(iw, cfL[lc], pdG[lc], pdI[lc]);
    }

    // --- 8 per-block partials: mask_-free base sums + pg + hm
    bool mk = (biou >= 0.5f);
    bool ob = (obits[thr >> 5] >> (thr & 31)) & 1u;
    float fmk = mk ? 1.f : 0.f, fnmk = 1.f - fmk, fob = ob ? 1.f : 0.f;
    float4 ha = io4[idx], hb = hm4[idx];
    float d0 = ha.x - hb.x, d1 = ha.y - hb.y, d2 = ha.z - hb.z, d3 = ha.w - hb.w;
    float vals[8] = {
        fmk,                          // c2 base  (sum mk)
        (1.f - bg) * fmk,             // sg base
        (1.f - biou) * fmk,           // si base
        cf * fob * fnmk,              // sint base (cf*ob*!mk)
        cf * cf * fnmk,               // spa base  (cf^2*!mk)
        fob * fnmk,                   // sga base  (ob*!mk)
        cf * cf,                      // pg
        d0 * d0 + d1 * d1 + d2 * d2 + d3 * d3   // hm
    };
#pragma unroll
    for (int k = 0; k < 8; ++k) {
        float vv = waveSum(vals[k]);
        if (lane == 0) red[k][wave] = vv;
    }
    __syncthreads();
    if (thr == 0) {
#pragma unroll
        for (int k = 0; k < 8; ++k)
            bpart[blk * 8 + k] = (double)(red[k][0] + red[k][1] + red[k][2] + red[k][3]);
    }
}

// ---------------------------------------------------------------------------
// Kernel D (slim, r10/r13-proven, unchanged): 16 blocks. Label pass; 60x48
// winner scan; dedup'd winner-cell corrections; 48-row partial sum; bacc row
// + fence + ticket; last block finalizes. Producer->consumer coherence via
// the kernel boundary (the only mechanism proven on this chip).
// ---------------------------------------------------------------------------
__global__ __launch_bounds__(256)
void kD(const float* __restrict__ out, const float* __restrict__ labels,
        const unsigned long long* __restrict__ gtpart, const float4* __restrict__ gtaux,
        const double* __restrict__ bpart,
        double* __restrict__ bacc, unsigned int* __restrict__ ticket,
        float* __restrict__ outp) {
    int b = blockIdx.x, thr = threadIdx.x;
    int wave = thr >> 6, lane = thr & 63;

    __shared__ int keys[NT];
    __shared__ unsigned int obits[NPB / 32];   // 384 words (full batch)
    __shared__ int wnL[NT];
    __shared__ float4 auxL[NT];
    __shared__ int finS;
    __shared__ double baccL[256];

    for (int w = thr; w < NPB / 32; w += 256) obits[w] = 0u;
    if (thr < NT) {
        const float* lp = labels + (b * NT + thr) * 5;
        keys[thr] = ((int)(lp[2] * (float)NGRID) << 6) | (int)(lp[1] * (float)NGRID);
    }
    __syncthreads();

    float sxy = 0.f, swh = 0.f, sig_ = 0.f, scnt = 0.f, sgou = 0.f, siou = 0.f;
    if (thr < NT) {
        // label pass
        int key = keys[thr];
        int occ = 0;
        for (int i = 0; i < thr; ++i)
            if (keys[i] == key) occ++;
        const float* lp = labels + (b * NT + thr) * 5;
        float bxf = lp[1] * (float)NGRID;
        float byf = lp[2] * (float)NGRID;
        float lw_ = lp[3], lh_ = lp[4];
        int gi = (int)bxf, gj = (int)byf;
        if (occ < NANCH) {
            int cell = (occ << 12) | (gj << 6) | gi;
            atomicOr(&obits[cell >> 5], 1u << (cell & 31));
            int base = ((b * NANCH * 5 + occ * 5) * NGRID + gj) * NGRID + gi;
            float xs = sigm(out[base]);
            float ys = sigm(out[base + NGRID * NGRID]);
            float ws = sigm(out[base + 2 * NGRID * NGRID]);
            float hs = sigm(out[base + 3 * NGRID * NGRID]);
            float cfl = sigm(out[base + 4 * NGRID * NGRID]);
            float tx = bxf - floorf(bxf);
            float ty = byf - floorf(byf);
            float dx = xs - tx, dy = ys - ty;
            sxy = dx * dx + dy * dy;
            float dw = __logf(ws) - __logf(lw_);
            float dh = __logf(hs) - __logf(lh_);
            swh = dw * dw + dh * dh;
            sig_ = cfl;
            scnt = 1.f;
        }
        // winner scan over this batch's 48 block winners for GT thr
        unsigned long long bestp = 0ull;
        int sbest = 0;
        for (int ss = 0; ss < NBPB; ++ss) {
            unsigned long long pk = gtpart[(b * NBPB + ss) * 64 + thr];
            if (pk > bestp) { bestp = pk; sbest = ss; }   // pk unique across ss
        }
        float4 aux = gtaux[(b * NBPB + sbest) * 64 + thr];
        wnL[thr] = (int)(0xFFFFFFFFu - (unsigned int)(bestp & 0xFFFFFFFFu));
        auxL[thr] = aux;
        sgou = 1.f - ford_inv((unsigned int)(bestp >> 32));
        siou = 1.f - aux.x;
    }
    __syncthreads();   // obits + wnL/auxL complete

    // dedup'd winner-cell corrections (first t claims the cell)
    float dc2 = 0.f, dsg = 0.f, dsi = 0.f, dsint = 0.f, dspa = 0.f, dsga = 0.f;
    if (thr < NT) {
        int wn = wnL[thr];
        bool uniq = true;
        for (int tp = 0; tp < thr; ++tp)
            if (wnL[tp] == wn) { uniq = false; break; }
        if (uniq) {
            float4 aux = auxL[thr];            // (iou_w, cf, pdg, pdi)
            bool mk = (aux.w >= 0.5f);
            bool ob = (obits[wn >> 5] >> (wn & 31)) & 1u;
            float fnmk = mk ? 0.f : 1.f;
            float obnmk = (ob ? 1.f : 0.f) * fnmk;
            dc2 = fnmk;
            dsg = (1.f - aux.z) * fnmk;
            dsi = (1.f - aux.w) * fnmk;
            dsint = aux.y * (1.f - obnmk);
            dspa = aux.y * aux.y * (mk ? 1.f : 0.f);
            dsga = 1.f - obnmk;
        }
    }

    // wave-0 reductions + 48-row partial sums
    double labD[6], corD[6], prtD[8];
    if (wave == 0) {
        labD[0] = (double)waveSum(sxy);
        labD[1] = (double)waveSum(swh);
        labD[2] = (double)waveSum(sig_);
        labD[3] = (double)waveSum(scnt);
        labD[4] = (double)waveSum(sgou);
        labD[5] = (double)waveSum(siou);
        corD[0] = (double)waveSum(dc2);
        corD[1] = (double)waveSum(dsg);
        corD[2] = (double)waveSum(dsi);
        corD[3] = (double)waveSum(dsint);
        corD[4] = (double)waveSum(dspa);
        corD[5] = (double)waveSum(dsga);
#pragma unroll
        for (int k = 0; k < 8; ++k) {
            double v = (lane < NBPB) ? bpart[(b * NBPB + lane) * 8 + k] : 0.0;
            prtD[k] = waveSumD(v);
        }
    }
    __syncthreads();

    // bacc row + release fence + ticket
    if (thr == 0) {
        double* row = &bacc[b * 16];
        row[0]  = prtD[0] + corD[0];   // c2
        row[1]  = prtD[1] + corD[1];   // sg
        row[2]  = prtD[2] + corD[2];   // si
        row[3]  = prtD[3] + corD[3];   // sinter
        row[4]  = prtD[4] + corD[4];   // spa
        row[5]  = prtD[5] + corD[5];   // sga
        row[6]  = labD[4];             // sgou
        row[7]  = labD[5];             // siou
        row[8]  = labD[0];             // sxy
        row[9]  = labD[1];             // swh
        row[10] = labD[2];             // ig
        row[11] = labD[3];             // cnt
        row[12] = prtD[6];             // pg
        row[13] = prtD[7];             // hm
        row[14] = 0.0; row[15] = 0.0;
        __threadfence();
        unsigned int old = atomicAdd(ticket, 1u);
        finS = (old == NBATCH - 1) ? 1 : 0;
    }
    __syncthreads();

    // finalize (last-finishing block; block-uniform branch)
    if (finS) {
        int bb = thr >> 4, k = thr & 15;
        baccL[thr] = atomicAdd(&bacc[bb * 16 + k], 0.0);   // coherent RMW read
        __syncthreads();
        if (thr == 0) {
            double cnt = 0, sxyT = 0, swhT = 0, igT = 0, pgT = 0, hmT = 0;
            double sgouT = 0, siouT = 0, gou2 = 0, iou2 = 0, confbT = 0;
            for (int q = 0; q < NBATCH; ++q) {
                const double* r = &baccL[q * 16];
                cnt += r[11]; sxyT += r[8]; swhT += r[9]; igT += r[10];
                pgT += r[12]; hmT += r[13];
                sgouT += r[6]; siouT += r[7];
                gou2 += r[1] / r[0];
                iou2 += r[2] / r[0];
                confbT += 1.0 - (2.0 * r[3] + 1.0) / (r[4] + r[5] + 1.0);
            }
            double lxy = sxyT / cnt;
            double lwh = swhT / cnt;
            double lgou = sgouT / (double)NLBL + gou2 / (double)NBATCH;
            double liou = siouT / (double)NLBL + iou2 / (double)NBATCH;
            double dice = (2.0 * igT + 1.0) / (pgT + cnt + 1.0);
            if (dice != dice) dice = 1.0;
            double lconf = 1.0 - dice + confbT / (double)NBATCH;
            double total = lxy + lwh + lconf + lgou;
            double hmv = hmT / (double)(4 * NCELL);
            outp[0] = (float)lxy;
            outp[1] = (float)lwh;
            outp[2] = (float)lconf;
            outp[3] = (float)liou;
            outp[4] = (float)lgou;
            outp[5] = (float)total;
            outp[6] = (float)hmv;
        }
    }
}

// ---------------------------------------------------------------------------
extern "C" void kernel_launch(void* const* d_in, const int* in_sizes, int n_in,
                              void* d_out, int out_size, void* d_ws, size_t ws_size,
                              hipStream_t stream) {
    const float* out_p  = (const float*)d_in[0];
    const float* labels = (const float*)d_in[1];
    const float4* io4   = (const float4*)d_in[2];
    const float4* hm4   = (const float4*)d_in[3];
    float* o = (float*)d_out;

    char* ws = (char*)d_ws;
    unsigned long long* gtpart = (unsigned long long*)(ws);            // 393216 B
    float4* gtaux = (float4*)(ws + 393216);                            // 786432 B
    double* bpart = (double*)(ws + 1179648);                           //  49152 B
    double* bacc  = (double*)(ws + 1228800);                           //   2048 B
    unsigned int* ticket = (unsigned int*)(ws + 1230848);              //     64 B
    // ~1.23 MB total; all consumed data fully written each call (kB zeroes
    // the ticket) — no memset, no zero-init ordering hazards. Producer ->
    // consumer crosses the kernel boundary (the only coherence mechanism
    // proven on this chip: r11/r12 intra-dispatch attempts both failed).

    hipLaunchKernelGGL(kB, dim3(NBLKB), dim3(256), 0, stream, out_p, labels, io4, hm4,
                       gtpart, gtaux, bpart, ticket);
    hipLaunchKernelGGL(kD, dim3(NBATCH), dim3(256), 0, stream, out_p, labels,
                       gtpart, gtaux, bpart, bacc, ticket, o);
}